// Round 5
// baseline (1422.722 us; speedup 1.0000x reference)
//
#include <hip/hip_runtime.h>
#include <hip/hip_bf16.h>

// Problem constants: B=128, N=1024, E=16384, ENTITY=100000, EMB=100, HID=100

typedef unsigned int u32;
typedef float f2 __attribute__((ext_vector_type(2)));

__device__ __forceinline__ float bflo(u32 u) {
    union { u32 i; float f; } v; v.i = u << 16; return v.f;
}
__device__ __forceinline__ float bfhi(u32 u) {
    union { u32 i; float f; } v; v.i = u & 0xffff0000u; return v.f;
}
__device__ __forceinline__ u32 f2bf1(float f) {
    union { float f; u32 u; } v; v.f = f;
    return (v.u + 0x7fffu + ((v.u >> 16) & 1u)) >> 16;   // RNE
}
__device__ __forceinline__ u32 packbf(float a, float b) {
    return f2bf1(a) | (f2bf1(b) << 16);
}
__device__ __forceinline__ float sigm(float x) { return 1.f / (1.f + __expf(-x)); }
__device__ __forceinline__ float tanh_fast(float x) {
    float e = __expf(2.f * x);
    return 1.f - 2.f / (e + 1.f);
}

// ---------------------------------------------------------------------------
// Kernel 1: embedding gather + GCN matmul.  support[n][h] (bf16 packed u32)
// ---------------------------------------------------------------------------
__global__ __launch_bounds__(256, 2)
void gcn_kernel(const int* __restrict__ nb, const float* __restrict__ emb,
                const float* __restrict__ w, u32* __restrict__ support)
{
    __shared__ float wl[10000];
    for (int i = threadIdx.x; i < 10000; i += 256) wl[i] = w[i];
    __syncthreads();

    const int n = blockIdx.x * 256 + threadIdx.x;
    const long long row = nb[n];
    const float4* __restrict__ xr = (const float4*)(emb + row * 100);

    float acc[100];
#pragma unroll
    for (int h = 0; h < 100; ++h) acc[h] = 0.f;

    for (int kk = 0; kk < 25; ++kk) {
        const float4 xv = xr[kk];
        const float xs[4] = { xv.x, xv.y, xv.z, xv.w };
#pragma unroll
        for (int q = 0; q < 4; ++q) {
            const float* wrow = &wl[(kk * 4 + q) * 100];
            const float xq = xs[q];
#pragma unroll
            for (int h4 = 0; h4 < 25; ++h4) {
                const float4 w4 = *(const float4*)(wrow + h4 * 4);
                acc[h4*4+0] = fmaf(xq, w4.x, acc[h4*4+0]);
                acc[h4*4+1] = fmaf(xq, w4.y, acc[h4*4+1]);
                acc[h4*4+2] = fmaf(xq, w4.z, acc[h4*4+2]);
                acc[h4*4+3] = fmaf(xq, w4.w, acc[h4*4+3]);
            }
        }
    }

    u32* __restrict__ o = support + (size_t)n * 50;
#pragma unroll
    for (int i = 0; i < 50; ++i) o[i] = packbf(acc[2*i], acc[2*i+1]);
}

// ---------------------------------------------------------------------------
// Kernel 2a: per-sample counting-sort into CSR order.
// ---------------------------------------------------------------------------
__global__ __launch_bounds__(256, 2)
void csr_build(const int* __restrict__ arow, const int* __restrict__ acol,
               const float* __restrict__ aval,
               int* __restrict__ offs, int2* __restrict__ csr)
{
    __shared__ int cnt[1024];
    __shared__ int part[256];
    __shared__ int offl[1024];

    const int b   = blockIdx.x;
    const int tid = threadIdx.x;
    const int*   rw = arow + b * 16384;
    const int*   cl = acol + b * 16384;
    const float* vl = aval + b * 16384;

    for (int i = tid; i < 1024; i += 256) cnt[i] = 0;
    __syncthreads();
    for (int e = tid; e < 16384; e += 256) atomicAdd(&cnt[rw[e]], 1);
    __syncthreads();

    int c[4]; int s = 0;
#pragma unroll
    for (int q = 0; q < 4; ++q) { c[q] = cnt[tid * 4 + q]; s += c[q]; }
    part[tid] = s;
    __syncthreads();
    for (int off = 1; off < 256; off <<= 1) {
        int v = (tid >= off) ? part[tid - off] : 0;
        __syncthreads();
        part[tid] += v;
        __syncthreads();
    }
    int run = part[tid] - s;
#pragma unroll
    for (int q = 0; q < 4; ++q) { offl[tid * 4 + q] = run; run += c[q]; }
    __syncthreads();

    for (int i = tid; i < 1024; i += 256) offs[b * 1025 + i] = offl[i];
    if (tid == 0) offs[b * 1025 + 1024] = 16384;

    int2* cs = csr + (size_t)b * 16384;
    for (int e = tid; e < 16384; e += 256) {
        const int r   = rw[e];
        const int pos = atomicAdd(&offl[r], 1);
        int2 cv; cv.x = cl[e]; cv.y = __float_as_int(vl[e]);
        cs[pos] = cv;
    }
}

// ---------------------------------------------------------------------------
// Kernel 2b: atomic-free CSR aggregate.  50 lanes/row.
// ---------------------------------------------------------------------------
__global__ __launch_bounds__(256, 4)
void spmm_agg(const int* __restrict__ offs, const int2* __restrict__ csr,
              const u32* __restrict__ support,
              const float* __restrict__ gcn_b, u32* __restrict__ seq)
{
    const int b    = blockIdx.y;
    const int lr   = threadIdx.x / 50;
    const int lane = threadIdx.x % 50;
    const int r    = blockIdx.x * 5 + lr;
    if (lr >= 5 || r >= 1024) return;

    const int e0 = offs[b * 1025 + r];
    const int e1 = offs[b * 1025 + r + 1];
    const int2* __restrict__ cs = csr + (size_t)b * 16384;
    const u32* __restrict__ supb = support + (size_t)b * 1024 * 50;

    float a0 = 0.f, a1 = 0.f;
    for (int e = e0; e < e1; ++e) {
        const int2 cv = cs[e];
        const float v = __int_as_float(cv.y);
        const u32 u = supb[(size_t)cv.x * 50 + lane];
        a0 = fmaf(v, bflo(u), a0);
        a1 = fmaf(v, bfhi(u), a1);
    }
    a0 += gcn_b[2 * lane];
    a1 += gcn_b[2 * lane + 1];
    seq[((size_t)b * 1024 + r) * 50 + lane] = packbf(a0, a1);
}

// ---------------------------------------------------------------------------
// Kernel 3: gx GEMM.  gx[m][g*50+jw] packs units (2jw,2jw+1) of gate g, bf16.
// ---------------------------------------------------------------------------
__global__ __launch_bounds__(256, 2)
void gx_gemm0(const u32* __restrict__ seq, const float* __restrict__ w_ih,
              const float* __restrict__ b_ih, u32* __restrict__ gxW,
              int c0, int ctl, int CT)
{
    __shared__ float wl[10000];
    const int g    = blockIdx.x % 3;
    const int tile = blockIdx.x / 3;
    const int tid  = threadIdx.x;

    for (int i = tid; i < 10000; i += 256)
        wl[(i % 100) * 100 + (i / 100)] = w_ih[g * 10000 + i];   // transpose
    __syncthreads();

    const int m = tile * 256 + tid;              // 0 .. 128*CT-1
    const int b = m >> ctl;
    const int t = m & (CT - 1);
    const uint2* sr2 = (const uint2*)(seq + ((size_t)b * 1024 + c0 + t) * 50);

    float acc[100];
    const float4* bi4 = (const float4*)(b_ih + g * 100);
#pragma unroll
    for (int j4 = 0; j4 < 25; ++j4) {
        const float4 bv = bi4[j4];
        acc[j4*4+0] = bv.x; acc[j4*4+1] = bv.y; acc[j4*4+2] = bv.z; acc[j4*4+3] = bv.w;
    }

    for (int kk = 0; kk < 25; ++kk) {
        const uint2 up = sr2[kk];
        const float xs[4] = { bflo(up.x), bfhi(up.x), bflo(up.y), bfhi(up.y) };
#pragma unroll
        for (int q = 0; q < 4; ++q) {
            const float* wrow = &wl[(kk * 4 + q) * 100];
            const float xq = xs[q];
#pragma unroll
            for (int j4 = 0; j4 < 25; ++j4) {
                const float4 w4 = *(const float4*)(wrow + j4 * 4);
                acc[j4*4+0] = fmaf(xq, w4.x, acc[j4*4+0]);
                acc[j4*4+1] = fmaf(xq, w4.y, acc[j4*4+1]);
                acc[j4*4+2] = fmaf(xq, w4.z, acc[j4*4+2]);
                acc[j4*4+3] = fmaf(xq, w4.w, acc[j4*4+3]);
            }
        }
    }

    u32* og = gxW + (size_t)m * 150 + g * 50;
#pragma unroll
    for (int i = 0; i < 50; ++i) og[i] = packbf(acc[2*i], acc[2*i+1]);
}

// ---------------------------------------------------------------------------
// Kernel 4 (v4): GRU recurrence, 1 sample/block, 256 threads (4 waves).
// Unit j handled by the lane PAIR (2*(j%25), 2*(j%25)+1) of wave j/25.
// Each lane holds the 3 gate half-rows of W_hh (k float4-groups with q%2==p,
// ~156 VGPR); partials combine with ONE __shfl_xor (no LDS, no extra
// barrier); h[j] kept in a register by its pair; h vector ping-pongs through
// LDS with ONE barrier per step.  gx bf16, register prefetch distance 2.
// ---------------------------------------------------------------------------
__global__ __launch_bounds__(256, 1)
void gru_v4(const u32* __restrict__ gxR, size_t sampStride,
            const float* __restrict__ w_hh, const float* __restrict__ b_hh,
            float* __restrict__ hg, const float* __restrict__ fc1_w,
            const float* __restrict__ fc1_b, float* __restrict__ out,
            int first, int last, int CT)
{
    __shared__ float h[2][100];

    const int tid  = threadIdx.x;
    const int samp = blockIdx.x;
    const int wave = tid >> 6;
    const int lane = tid & 63;
    const bool act = (lane < 50);
    const int  j   = wave * 25 + (lane >> 1);   // unit 0..99
    const int  p   = lane & 1;                  // k-half parity
    const int  jodd = j & 1;

    // ---- one-time: 3 gate half-rows into registers ----
    f2 wr[26], wz[26], wn[26];
    float bhr = 0.f, bhz = 0.f, bhn = 0.f, hcur = 0.f;
    if (act) {
        const float* rrow = w_hh + (size_t)j * 100;
        const float* zrow = w_hh + (size_t)(100 + j) * 100;
        const float* nrow = w_hh + (size_t)(200 + j) * 100;
#pragma unroll
        for (int i = 0; i < 13; ++i) {
            const int q = 2 * i + p;
            if (q < 25) {
                const float4 a = *(const float4*)(rrow + 4 * q);
                wr[2*i] = (f2){a.x, a.y}; wr[2*i+1] = (f2){a.z, a.w};
                const float4 b = *(const float4*)(zrow + 4 * q);
                wz[2*i] = (f2){b.x, b.y}; wz[2*i+1] = (f2){b.z, b.w};
                const float4 c = *(const float4*)(nrow + 4 * q);
                wn[2*i] = (f2){c.x, c.y}; wn[2*i+1] = (f2){c.z, c.w};
            }
        }
        bhr = b_hh[j]; bhz = b_hh[100 + j]; bhn = b_hh[200 + j];
        hcur = first ? 0.f : hg[samp * 100 + j];
        if (!p) h[0][j] = hcur;
    }
    __syncthreads();

    const u32* gp = gxR + (size_t)samp * sampStride + (j >> 1);
    u32 a0 = 0, a1 = 0, a2 = 0, b0 = 0, b1 = 0, b2 = 0;
    if (act) {
        a0 = gp[0];   a1 = gp[50];  a2 = gp[100];       // t = 0
        b0 = gp[150]; b1 = gp[200]; b2 = gp[250];       // t = 1
    }
    int par = 0;

    auto stepf = [&](int t, u32& x0, u32& x1, u32& x2) {
        f2 ar = {0.f,0.f}, az = {0.f,0.f}, an = {0.f,0.f};
        if (act) {
#pragma unroll
            for (int i = 0; i < 13; ++i) {
                const int q = 2 * i + p;
                if (q < 25) {
                    const float4 hv = *(const float4*)(&h[par][4 * q]);
                    const f2 hA = (f2){hv.x, hv.y};
                    const f2 hB = (f2){hv.z, hv.w};
                    ar += wr[2*i] * hA; ar += wr[2*i+1] * hB;
                    az += wz[2*i] * hA; az += wz[2*i+1] * hB;
                    an += wn[2*i] * hA; an += wn[2*i+1] * hB;
                }
            }
        }
        const u32 c0 = x0, c1 = x1, c2 = x2;
        if (act && t + 2 < CT) {
            const u32* q2 = gp + (size_t)(t + 2) * 150;
            x0 = q2[0]; x1 = q2[50]; x2 = q2[100];
        }
        if (act) {
            float sr = ar.x + ar.y;
            float sz = az.x + az.y;
            float sn = an.x + an.y;
            sr += __shfl_xor(sr, 1);                     // combine k-halves
            sz += __shfl_xor(sz, 1);
            sn += __shfl_xor(sn, 1);
            const float gxr = jodd ? bfhi(c0) : bflo(c0);
            const float gxz = jodd ? bfhi(c1) : bflo(c1);
            const float gxn = jodd ? bfhi(c2) : bflo(c2);
            const float rg = sigm(gxr + sr + bhr);
            const float zg = sigm(gxz + sz + bhz);
            const float ng = tanh_fast(gxn + rg * (sn + bhn));
            hcur = (1.f - zg) * ng + zg * hcur;
            if (!p) h[par ^ 1][j] = hcur;
        }
        __syncthreads();
        par ^= 1;
    };

    for (int t = 0; t < CT; t += 2) {
        stepf(t,     a0, a1, a2);
        stepf(t + 1, b0, b1, b2);
    }

    if (act && !p) {
        hg[samp * 100 + j] = hcur;
        if (last) {
            const float4* fw = (const float4*)(fc1_w + (size_t)j * 100);
            float s0 = 0.f, s1 = 0.f, s2 = 0.f, s3 = 0.f;
#pragma unroll
            for (int kk = 0; kk < 25; ++kk) {
                const float4 wv = fw[kk];
                const float4 hv = *(const float4*)(&h[par][kk * 4]);
                s0 = fmaf(wv.x, hv.x, s0);
                s1 = fmaf(wv.y, hv.y, s1);
                s2 = fmaf(wv.z, hv.z, s2);
                s3 = fmaf(wv.w, hv.w, s3);
            }
            const float s = (s0 + s1) + (s2 + s3) + fc1_b[j];
            out[samp * 100 + j] = fmaxf(s, 0.f);
        }
    }
}

// ---------------------------------------------------------------------------
extern "C" void kernel_launch(void* const* d_in, const int* in_sizes, int n_in,
                              void* d_out, int out_size, void* d_ws, size_t ws_size,
                              hipStream_t stream)
{
    const int*   neighbors = (const int*)  d_in[0];
    const int*   adj_row   = (const int*)  d_in[1];
    const int*   adj_col   = (const int*)  d_in[2];
    const float* adj_val   = (const float*)d_in[3];
    const float* emb       = (const float*)d_in[4];
    const float* gcn_w     = (const float*)d_in[5];
    const float* gcn_b     = (const float*)d_in[6];
    const float* w_ih      = (const float*)d_in[7];
    const float* w_hh      = (const float*)d_in[8];
    const float* b_ih      = (const float*)d_in[9];
    const float* b_hh      = (const float*)d_in[10];
    const float* fc1_w     = (const float*)d_in[11];
    const float* fc1_b     = (const float*)d_in[12];
    float* out = (float*)d_out;

    char* ws = (char*)d_ws;
    const size_t seq_bytes     = (size_t)128 * 1024 * 50 * 4;    // 26,214,400
    const size_t hg_bytes      = 128 * 100 * 4;                  // 51,200
    const size_t support_bytes = (size_t)128 * 1024 * 50 * 4;    // 26,214,400
    const size_t offs_bytes    = (size_t)128 * 1025 * 4;         // 524,800

    u32*   seq = (u32*)ws;
    float* hg  = (float*)(ws + seq_bytes);
    char*  rest = ws + seq_bytes + hg_bytes;
    const size_t rest_avail = ws_size - seq_bytes - hg_bytes;

    // Phase 1: support + CSR live in `rest`, dead before gx overwrites it.
    u32*  support = (u32*)rest;
    int*  offs    = (int*)(rest + support_bytes);
    int2* csr     = (int2*)(rest + support_bytes + offs_bytes);

    gcn_kernel<<<512, 256, 0, stream>>>(neighbors, emb, gcn_w, support);
    csr_build<<<128, 256, 0, stream>>>(adj_row, adj_col, adj_val, offs, csr);
    spmm_agg<<<dim3(205, 128), 256, 0, stream>>>(offs, csr, support, gcn_b, seq);

    const size_t gx_full = (size_t)128 * 1024 * 150 * 4;         // 78,643,200
    u32* gx = (u32*)rest;

    if (rest_avail >= gx_full) {
        gx_gemm0<<<1536, 256, 0, stream>>>(seq, w_ih, b_ih, gx, 0, 10, 1024);
        gru_v4<<<128, 256, 0, stream>>>(gx, (size_t)1024 * 150, w_hh, b_hh, hg,
                                        fc1_w, fc1_b, out, 1, 1, 1024);
    } else {
        int CT = 512, ctl = 9;
        while (CT > 8 && (size_t)128 * CT * 150 * 4 > rest_avail) { CT >>= 1; --ctl; }
        const int nch = 1024 / CT;
        for (int c = 0; c < nch; ++c) {
            gx_gemm0<<<3 * (128 * CT / 256), 256, 0, stream>>>(seq, w_ih, b_ih, gx,
                                                               c * CT, ctl, CT);
            gru_v4<<<128, 256, 0, stream>>>(gx, (size_t)CT * 150, w_hh, b_hh, hg,
                                            fc1_w, fc1_b, out,
                                            (c == 0) ? 1 : 0, (c == nch - 1) ? 1 : 0, CT);
        }
    }
}

// Round 7
// 1330.442 us; speedup vs baseline: 1.0694x; 1.0694x over previous
//
#include <hip/hip_runtime.h>
#include <hip/hip_bf16.h>

// Problem constants: B=128, N=1024, E=16384, ENTITY=100000, EMB=100, HID=100

typedef unsigned int u32;
typedef float f2 __attribute__((ext_vector_type(2)));

__device__ __forceinline__ float bflo(u32 u) {
    union { u32 i; float f; } v; v.i = u << 16; return v.f;
}
__device__ __forceinline__ float bfhi(u32 u) {
    union { u32 i; float f; } v; v.i = u & 0xffff0000u; return v.f;
}
__device__ __forceinline__ u32 f2bf1(float f) {
    union { float f; u32 u; } v; v.f = f;
    return (v.u + 0x7fffu + ((v.u >> 16) & 1u)) >> 16;   // RNE
}
__device__ __forceinline__ u32 packbf(float a, float b) {
    return f2bf1(a) | (f2bf1(b) << 16);
}
__device__ __forceinline__ float sigm(float x) { return 1.f / (1.f + __expf(-x)); }
__device__ __forceinline__ float tanh_fast(float x) {
    float e = __expf(2.f * x);
    return 1.f - 2.f / (e + 1.f);
}
// Pin a 64-bit value (f2 pair) into VGPRs: the empty asm "modifies" it, so the
// compiler cannot rematerialize it by re-loading from memory every timestep
// (the round-2..5 disease: VGPR_Count 52/88/96 << declared weights).
__device__ __forceinline__ void pin2(f2& x) {
    double& d = reinterpret_cast<double&>(x);
    asm volatile("" : "+v"(d));
}
__device__ __forceinline__ void pinf(float& x) { asm volatile("" : "+v"(x)); }

// ---------------------------------------------------------------------------
// Kernel 1: embedding gather + GCN matmul.  support[n][h] (bf16 packed u32)
// ---------------------------------------------------------------------------
__global__ __launch_bounds__(256, 2)
void gcn_kernel(const int* __restrict__ nb, const float* __restrict__ emb,
                const float* __restrict__ w, u32* __restrict__ support)
{
    __shared__ float wl[10000];
    for (int i = threadIdx.x; i < 10000; i += 256) wl[i] = w[i];
    __syncthreads();

    const int n = blockIdx.x * 256 + threadIdx.x;
    const long long row = nb[n];
    const float4* __restrict__ xr = (const float4*)(emb + row * 100);

    float acc[100];
#pragma unroll
    for (int h = 0; h < 100; ++h) acc[h] = 0.f;

    for (int kk = 0; kk < 25; ++kk) {
        const float4 xv = xr[kk];
        const float xs[4] = { xv.x, xv.y, xv.z, xv.w };
#pragma unroll
        for (int q = 0; q < 4; ++q) {
            const float* wrow = &wl[(kk * 4 + q) * 100];
            const float xq = xs[q];
#pragma unroll
            for (int h4 = 0; h4 < 25; ++h4) {
                const float4 w4 = *(const float4*)(wrow + h4 * 4);
                acc[h4*4+0] = fmaf(xq, w4.x, acc[h4*4+0]);
                acc[h4*4+1] = fmaf(xq, w4.y, acc[h4*4+1]);
                acc[h4*4+2] = fmaf(xq, w4.z, acc[h4*4+2]);
                acc[h4*4+3] = fmaf(xq, w4.w, acc[h4*4+3]);
            }
        }
    }

    u32* __restrict__ o = support + (size_t)n * 50;
#pragma unroll
    for (int i = 0; i < 50; ++i) o[i] = packbf(acc[2*i], acc[2*i+1]);
}

// ---------------------------------------------------------------------------
// Kernel 2a: per-sample counting-sort into CSR order.
// RACE FIX (r6): barrier between the offs-copy and the scatter loop, which
// reuses offl[] as running cursors — without it a fast wave's atomicAdd
// corrupts offsets a slow wave is still copying (0.139 absmax divergence).
// ---------------------------------------------------------------------------
__global__ __launch_bounds__(256, 2)
void csr_build(const int* __restrict__ arow, const int* __restrict__ acol,
               const float* __restrict__ aval,
               int* __restrict__ offs, int2* __restrict__ csr)
{
    __shared__ int cnt[1024];
    __shared__ int part[256];
    __shared__ int offl[1024];

    const int b   = blockIdx.x;
    const int tid = threadIdx.x;
    const int*   rw = arow + b * 16384;
    const int*   cl = acol + b * 16384;
    const float* vl = aval + b * 16384;

    for (int i = tid; i < 1024; i += 256) cnt[i] = 0;
    __syncthreads();
    for (int e = tid; e < 16384; e += 256) atomicAdd(&cnt[rw[e]], 1);
    __syncthreads();

    int c[4]; int s = 0;
#pragma unroll
    for (int q = 0; q < 4; ++q) { c[q] = cnt[tid * 4 + q]; s += c[q]; }
    part[tid] = s;
    __syncthreads();
    for (int off = 1; off < 256; off <<= 1) {
        int v = (tid >= off) ? part[tid - off] : 0;
        __syncthreads();
        part[tid] += v;
        __syncthreads();
    }
    int run = part[tid] - s;
#pragma unroll
    for (int q = 0; q < 4; ++q) { offl[tid * 4 + q] = run; run += c[q]; }
    __syncthreads();

    for (int i = tid; i < 1024; i += 256) offs[b * 1025 + i] = offl[i];
    if (tid == 0) offs[b * 1025 + 1024] = 16384;
    __syncthreads();                       // <-- the fix

    int2* cs = csr + (size_t)b * 16384;
    for (int e = tid; e < 16384; e += 256) {
        const int r   = rw[e];
        const int pos = atomicAdd(&offl[r], 1);
        int2 cv; cv.x = cl[e]; cv.y = __float_as_int(vl[e]);
        cs[pos] = cv;
    }
}

// ---------------------------------------------------------------------------
// Kernel 2b: atomic-free CSR aggregate.  50 lanes/row.
// ---------------------------------------------------------------------------
__global__ __launch_bounds__(256, 4)
void spmm_agg(const int* __restrict__ offs, const int2* __restrict__ csr,
              const u32* __restrict__ support,
              const float* __restrict__ gcn_b, u32* __restrict__ seq)
{
    const int b    = blockIdx.y;
    const int lr   = threadIdx.x / 50;
    const int lane = threadIdx.x % 50;
    const int r    = blockIdx.x * 5 + lr;
    if (lr >= 5 || r >= 1024) return;

    const int e0 = offs[b * 1025 + r];
    const int e1 = offs[b * 1025 + r + 1];
    const int2* __restrict__ cs = csr + (size_t)b * 16384;
    const u32* __restrict__ supb = support + (size_t)b * 1024 * 50;

    float a0 = 0.f, a1 = 0.f;
    for (int e = e0; e < e1; ++e) {
        const int2 cv = cs[e];
        const float v = __int_as_float(cv.y);
        const u32 u = supb[(size_t)cv.x * 50 + lane];
        a0 = fmaf(v, bflo(u), a0);
        a1 = fmaf(v, bfhi(u), a1);
    }
    a0 += gcn_b[2 * lane];
    a1 += gcn_b[2 * lane + 1];
    seq[((size_t)b * 1024 + r) * 50 + lane] = packbf(a0, a1);
}

// ---------------------------------------------------------------------------
// Kernel 3: gx GEMM.  gx[m][g*50+jw] packs units (2jw,2jw+1) of gate g, bf16.
// ---------------------------------------------------------------------------
__global__ __launch_bounds__(256, 2)
void gx_gemm0(const u32* __restrict__ seq, const float* __restrict__ w_ih,
              const float* __restrict__ b_ih, u32* __restrict__ gxW,
              int c0, int ctl, int CT)
{
    __shared__ float wl[10000];
    const int g    = blockIdx.x % 3;
    const int tile = blockIdx.x / 3;
    const int tid  = threadIdx.x;

    for (int i = tid; i < 10000; i += 256)
        wl[(i % 100) * 100 + (i / 100)] = w_ih[g * 10000 + i];   // transpose
    __syncthreads();

    const int m = tile * 256 + tid;              // 0 .. 128*CT-1
    const int b = m >> ctl;
    const int t = m & (CT - 1);
    const uint2* sr2 = (const uint2*)(seq + ((size_t)b * 1024 + c0 + t) * 50);

    float acc[100];
    const float4* bi4 = (const float4*)(b_ih + g * 100);
#pragma unroll
    for (int j4 = 0; j4 < 25; ++j4) {
        const float4 bv = bi4[j4];
        acc[j4*4+0] = bv.x; acc[j4*4+1] = bv.y; acc[j4*4+2] = bv.z; acc[j4*4+3] = bv.w;
    }

    for (int kk = 0; kk < 25; ++kk) {
        const uint2 up = sr2[kk];
        const float xs[4] = { bflo(up.x), bfhi(up.x), bflo(up.y), bfhi(up.y) };
#pragma unroll
        for (int q = 0; q < 4; ++q) {
            const float* wrow = &wl[(kk * 4 + q) * 100];
            const float xq = xs[q];
#pragma unroll
            for (int j4 = 0; j4 < 25; ++j4) {
                const float4 w4 = *(const float4*)(wrow + j4 * 4);
                acc[j4*4+0] = fmaf(xq, w4.x, acc[j4*4+0]);
                acc[j4*4+1] = fmaf(xq, w4.y, acc[j4*4+1]);
                acc[j4*4+2] = fmaf(xq, w4.z, acc[j4*4+2]);
                acc[j4*4+3] = fmaf(xq, w4.w, acc[j4*4+3]);
            }
        }
    }

    u32* og = gxW + (size_t)m * 150 + g * 50;
#pragma unroll
    for (int i = 0; i < 50; ++i) og[i] = packbf(acc[2*i], acc[2*i+1]);
}

// ---------------------------------------------------------------------------
// Kernel 4 (v6): GRU recurrence, 1 sample/block, 256 threads (4 waves).
// = v4's packed-f2 structure (pair k-split, one __shfl_xor, h in register,
//   1 barrier/step)
// + PINNED f2 weights (64-bit asm pin; keeps v_pk_fma_f32 packing)
// + __launch_bounds__(256,1): 512-VGPR budget, no spill; extra occupancy is
//   worthless (128 blocks on 256 CUs)
// + gx register prefetch distance 4 (gx is 78MB >> L2; HBM latency ~900cyc)
// ---------------------------------------------------------------------------
__global__ __launch_bounds__(256, 1)
void gru_v6(const u32* __restrict__ gxR, size_t sampStride,
            const float* __restrict__ w_hh, const float* __restrict__ b_hh,
            float* __restrict__ hg, const float* __restrict__ fc1_w,
            const float* __restrict__ fc1_b, float* __restrict__ out,
            int first, int last, int CT)
{
    __shared__ float h[2][100];

    const int tid  = threadIdx.x;
    const int samp = blockIdx.x;
    const int wave = tid >> 6;
    const int lane = tid & 63;
    const bool act = (lane < 50);
    const int  j   = wave * 25 + (lane >> 1);   // unit 0..99
    const int  p   = lane & 1;                  // k-half parity
    const int  jodd = j & 1;

    // ---- one-time: 3 gate half-rows into PINNED f2 registers ----
    f2 wr[26], wz[26], wn[26];
    float bhr = 0.f, bhz = 0.f, bhn = 0.f, hcur = 0.f;
    if (act) {
        const float* rrow = w_hh + (size_t)j * 100;
        const float* zrow = w_hh + (size_t)(100 + j) * 100;
        const float* nrow = w_hh + (size_t)(200 + j) * 100;
#pragma unroll
        for (int i = 0; i < 13; ++i) {
            const int q = 2 * i + p;
            if (q < 25) {
                const float4 a = *(const float4*)(rrow + 4 * q);
                wr[2*i] = (f2){a.x, a.y}; wr[2*i+1] = (f2){a.z, a.w};
                const float4 b = *(const float4*)(zrow + 4 * q);
                wz[2*i] = (f2){b.x, b.y}; wz[2*i+1] = (f2){b.z, b.w};
                const float4 c = *(const float4*)(nrow + 4 * q);
                wn[2*i] = (f2){c.x, c.y}; wn[2*i+1] = (f2){c.z, c.w};
            } else {
                wr[2*i] = wr[2*i+1] = (f2){0.f, 0.f};
                wz[2*i] = wz[2*i+1] = (f2){0.f, 0.f};
                wn[2*i] = wn[2*i+1] = (f2){0.f, 0.f};
            }
        }
        bhr = b_hh[j]; bhz = b_hh[100 + j]; bhn = b_hh[200 + j];
        hcur = first ? 0.f : hg[samp * 100 + j];
        if (!p) h[0][j] = hcur;
    }
#pragma unroll
    for (int i = 0; i < 26; ++i) { pin2(wr[i]); pin2(wz[i]); pin2(wn[i]); }
    pinf(bhr); pinf(bhz); pinf(bhn);
    __syncthreads();

    const u32* gp = gxR + (size_t)samp * sampStride + (j >> 1);
    u32 pf[4][3];
#pragma unroll
    for (int s = 0; s < 4; ++s) {
        pf[s][0] = pf[s][1] = pf[s][2] = 0;
        if (act && s < CT) {
            const u32* q2 = gp + (size_t)s * 150;
            pf[s][0] = q2[0]; pf[s][1] = q2[50]; pf[s][2] = q2[100];
        }
    }
    int par = 0;

    auto stepf = [&](int t, u32* x) {
        f2 ar0 = {0.f,0.f}, ar1 = {0.f,0.f};
        f2 az0 = {0.f,0.f}, az1 = {0.f,0.f};
        f2 an0 = {0.f,0.f}, an1 = {0.f,0.f};
        if (act) {
#pragma unroll
            for (int i = 0; i < 13; ++i) {
                const int q = 2 * i + p;
                if (q < 25) {
                    const float4 hv = *(const float4*)(&h[par][4 * q]);
                    const f2 hA = (f2){hv.x, hv.y};
                    const f2 hB = (f2){hv.z, hv.w};
                    ar0 += wr[2*i] * hA; ar1 += wr[2*i+1] * hB;
                    az0 += wz[2*i] * hA; az1 += wz[2*i+1] * hB;
                    an0 += wn[2*i] * hA; an1 += wn[2*i+1] * hB;
                }
            }
        }
        const u32 c0 = x[0], c1 = x[1], c2 = x[2];
        if (act && t + 4 < CT) {                         // prefetch distance 4
            const u32* q2 = gp + (size_t)(t + 4) * 150;
            x[0] = q2[0]; x[1] = q2[50]; x[2] = q2[100];
        }
        if (act) {
            float sr = (ar0.x + ar0.y) + (ar1.x + ar1.y);
            float sz = (az0.x + az0.y) + (az1.x + az1.y);
            float sn = (an0.x + an0.y) + (an1.x + an1.y);
            sr += __shfl_xor(sr, 1);                     // combine k-halves
            sz += __shfl_xor(sz, 1);
            sn += __shfl_xor(sn, 1);
            const float gxr = jodd ? bfhi(c0) : bflo(c0);
            const float gxz = jodd ? bfhi(c1) : bflo(c1);
            const float gxn = jodd ? bfhi(c2) : bflo(c2);
            const float rg = sigm(gxr + sr + bhr);
            const float zg = sigm(gxz + sz + bhz);
            const float ng = tanh_fast(gxn + rg * (sn + bhn));
            hcur = (1.f - zg) * ng + zg * hcur;
            if (!p) h[par ^ 1][j] = hcur;
        }
        __syncthreads();
        par ^= 1;
    };

    for (int t = 0; t < CT; t += 4) {
        stepf(t,     pf[0]);
        stepf(t + 1, pf[1]);
        stepf(t + 2, pf[2]);
        stepf(t + 3, pf[3]);
    }

    if (act && !p) {
        hg[samp * 100 + j] = hcur;
        if (last) {
            const float4* fw = (const float4*)(fc1_w + (size_t)j * 100);
            float s0 = 0.f, s1 = 0.f, s2 = 0.f, s3 = 0.f;
#pragma unroll
            for (int kk = 0; kk < 25; ++kk) {
                const float4 wv = fw[kk];
                const float4 hv = *(const float4*)(&h[par][kk * 4]);
                s0 = fmaf(wv.x, hv.x, s0);
                s1 = fmaf(wv.y, hv.y, s1);
                s2 = fmaf(wv.z, hv.z, s2);
                s3 = fmaf(wv.w, hv.w, s3);
            }
            const float s = (s0 + s1) + (s2 + s3) + fc1_b[j];
            out[samp * 100 + j] = fmaxf(s, 0.f);
        }
    }
}

// ---------------------------------------------------------------------------
extern "C" void kernel_launch(void* const* d_in, const int* in_sizes, int n_in,
                              void* d_out, int out_size, void* d_ws, size_t ws_size,
                              hipStream_t stream)
{
    const int*   neighbors = (const int*)  d_in[0];
    const int*   adj_row   = (const int*)  d_in[1];
    const int*   adj_col   = (const int*)  d_in[2];
    const float* adj_val   = (const float*)d_in[3];
    const float* emb       = (const float*)d_in[4];
    const float* gcn_w     = (const float*)d_in[5];
    const float* gcn_b     = (const float*)d_in[6];
    const float* w_ih      = (const float*)d_in[7];
    const float* w_hh      = (const float*)d_in[8];
    const float* b_ih      = (const float*)d_in[9];
    const float* b_hh      = (const float*)d_in[10];
    const float* fc1_w     = (const float*)d_in[11];
    const float* fc1_b     = (const float*)d_in[12];
    float* out = (float*)d_out;

    char* ws = (char*)d_ws;
    const size_t seq_bytes     = (size_t)128 * 1024 * 50 * 4;    // 26,214,400
    const size_t hg_bytes      = 128 * 100 * 4;                  // 51,200
    const size_t support_bytes = (size_t)128 * 1024 * 50 * 4;    // 26,214,400
    const size_t offs_bytes    = (size_t)128 * 1025 * 4;         // 524,800

    u32*   seq = (u32*)ws;
    float* hg  = (float*)(ws + seq_bytes);
    char*  rest = ws + seq_bytes + hg_bytes;
    const size_t rest_avail = ws_size - seq_bytes - hg_bytes;

    // Phase 1: support + CSR live in `rest`, dead before gx overwrites it.
    u32*  support = (u32*)rest;
    int*  offs    = (int*)(rest + support_bytes);
    int2* csr     = (int2*)(rest + support_bytes + offs_bytes);

    gcn_kernel<<<512, 256, 0, stream>>>(neighbors, emb, gcn_w, support);
    csr_build<<<128, 256, 0, stream>>>(adj_row, adj_col, adj_val, offs, csr);
    spmm_agg<<<dim3(205, 128), 256, 0, stream>>>(offs, csr, support, gcn_b, seq);

    const size_t gx_full = (size_t)128 * 1024 * 150 * 4;         // 78,643,200
    u32* gx = (u32*)rest;

    if (rest_avail >= gx_full) {
        gx_gemm0<<<1536, 256, 0, stream>>>(seq, w_ih, b_ih, gx, 0, 10, 1024);
        gru_v6<<<128, 256, 0, stream>>>(gx, (size_t)1024 * 150, w_hh, b_hh, hg,
                                        fc1_w, fc1_b, out, 1, 1, 1024);
    } else {
        int CT = 512, ctl = 9;
        while (CT > 8 && (size_t)128 * CT * 150 * 4 > rest_avail) { CT >>= 1; --ctl; }
        const int nch = 1024 / CT;
        for (int c = 0; c < nch; ++c) {
            gx_gemm0<<<3 * (128 * CT / 256), 256, 0, stream>>>(seq, w_ih, b_ih, gx,
                                                               c * CT, ctl, CT);
            gru_v6<<<128, 256, 0, stream>>>(gx, (size_t)CT * 150, w_hh, b_hh, hg,
                                            fc1_w, fc1_b, out,
                                            (c == 0) ? 1 : 0, (c == nch - 1) ? 1 : 0, CT);
        }
    }
}